// Round 5
// baseline (690.940 us; speedup 1.0000x reference)
//
#include <hip/hip_runtime.h>
#include <hip/hip_bf16.h>

// ---- problem constants ----
#define BB    16
#define TT    1024
#define MTOK  (BB*TT)     // 16384 tokens
#define IDIM_ 345
#define KPAD  384         // padded to /64 for BK=64
#define LL    4
#define DD_   256
#define FF_   1024
#define EPS_  1e-5f
#define QSCL  0.18033688f   // 0.125 * log2(e)

typedef __bf16 bf16;
typedef bf16 bf16x8 __attribute__((ext_vector_type(8)));
typedef float f32x4 __attribute__((ext_vector_type(4)));

static __device__ __forceinline__ f32x4 MFMA(bf16x8 a, bf16x8 b, f32x4 c) {
  return __builtin_amdgcn_mfma_f32_16x16x32_bf16(a, b, c, 0, 0, 0);
}
static __device__ __forceinline__ unsigned bfbits(float x) {
  return (unsigned)__builtin_bit_cast(unsigned short, (bf16)x);
}
static __device__ __forceinline__ bf16x8 ld_bf8(const void* p) {
  return *reinterpret_cast<const bf16x8*>(p);
}
static __device__ __forceinline__ void gload_lds16(const bf16* g, void* l) {
  __builtin_amdgcn_global_load_lds(
      (const __attribute__((address_space(1))) void*)g,
      (__attribute__((address_space(3))) void*)l, 16, 0, 0);
}

// ---- conversion kernels ----
// x [rows,345] f32 -> [rows,384] bf16; 4 outputs per thread, uint2 store
__global__ void k_convert_pad(const float* __restrict__ src, bf16* __restrict__ dst) {
  int idx = blockIdx.x * 256 + threadIdx.x;          // quad index
  if (idx >= MTOK * (KPAD / 4)) return;
  int r = idx / (KPAD / 4), c0 = (idx % (KPAD / 4)) * 4;
  const float* s = src + (long)r * IDIM_ + c0;
  float v0 = (c0 + 0 < IDIM_) ? s[0] : 0.f;
  float v1 = (c0 + 1 < IDIM_) ? s[1] : 0.f;
  float v2 = (c0 + 2 < IDIM_) ? s[2] : 0.f;
  float v3 = (c0 + 3 < IDIM_) ? s[3] : 0.f;
  uint2 pk;
  pk.x = bfbits(v0) | (bfbits(v1) << 16);
  pk.y = bfbits(v2) | (bfbits(v3) << 16);
  *reinterpret_cast<uint2*>(dst + (long)r * KPAD + c0) = pk;
}

__global__ void k_wt_convert(const float* __restrict__ src, bf16* __restrict__ dst,
                             int K, int N, int Kp) {
  int idx = blockIdx.x * 256 + threadIdx.x;
  if (idx >= N * Kp) return;
  int n = idx / Kp, kk = idx % Kp;
  dst[idx] = (kk < K) ? (bf16)src[(long)kk * N + n] : (bf16)0.f;
}

// LDS-tiled 64x64 transpose: [K,N] f32 -> [N,K] bf16 (coalesced both sides)
__global__ __launch_bounds__(256)
void k_wt_all(const float* __restrict__ Wq, const float* __restrict__ Wk,
              const float* __restrict__ Wv, const float* __restrict__ Wo,
              const float* __restrict__ W1, const float* __restrict__ W2,
              bf16* __restrict__ Wqkvt, bf16* __restrict__ Wot,
              bf16* __restrict__ W1t, bf16* __restrict__ W2t) {
  __shared__ float tile[64][65];
  const int s = blockIdx.y, m = s >> 2, i = s & 3;
  const float* src; bf16* dst; int K, N;
  switch (m) {
    case 0: src = Wq + (long)i*65536;  dst = Wqkvt + (long)i*196608;          K=256;  N=256;  break;
    case 1: src = Wk + (long)i*65536;  dst = Wqkvt + (long)i*196608 + 65536;  K=256;  N=256;  break;
    case 2: src = Wv + (long)i*65536;  dst = Wqkvt + (long)i*196608 + 131072; K=256;  N=256;  break;
    case 3: src = Wo + (long)i*65536;  dst = Wot + (long)i*65536;             K=256;  N=256;  break;
    case 4: src = W1 + (long)i*262144; dst = W1t + (long)i*262144;            K=256;  N=1024; break;
    default:src = W2 + (long)i*262144; dst = W2t + (long)i*262144;            K=1024; N=256;  break;
  }
  const int tiles_n = N >> 6, ntiles = (K >> 6) * tiles_n;
  if (blockIdx.x >= ntiles) return;
  const int tk = blockIdx.x / tiles_n, tn = blockIdx.x % tiles_n;
  const int t = threadIdx.x, rq = t >> 6, cl = t & 63;
  #pragma unroll
  for (int i2 = 0; i2 < 16; i2++)
    tile[rq * 16 + i2][cl] = src[(long)(tk * 64 + rq * 16 + i2) * N + tn * 64 + cl];
  __syncthreads();
  #pragma unroll
  for (int i2 = 0; i2 < 16; i2++)
    dst[(long)(tn * 64 + rq * 16 + i2) * K + tk * 64 + cl] = (bf16)tile[cl][rq * 16 + i2];
}

__global__ void k_bias_concat(const float* __restrict__ bq, const float* __restrict__ bk,
                              const float* __restrict__ bv, float* __restrict__ bqkv) {
  int idx = blockIdx.x * 256 + threadIdx.x;
  if (idx >= LL * 768) return;
  int i = idx / 768, j = idx % 768;
  float v = (j < 256) ? bq[i*256 + j] : (j < 512 ? bk[i*256 + j - 256] : bv[i*256 + j - 512]);
  bqkv[idx] = v;
}

// ---- LayerNorm: one wave per row of 256 ----
__global__ __launch_bounds__(256)
void k_ln(const float* __restrict__ in, float* __restrict__ outf,
          bf16* __restrict__ outb, const float* __restrict__ s,
          const float* __restrict__ b) {
  const int wave = threadIdx.x >> 6, lane = threadIdx.x & 63;
  const int row = blockIdx.x * 4 + wave;
  const float4 xv = *reinterpret_cast<const float4*>(in + (long)row * DD_ + lane * 4);
  float sum = xv.x + xv.y + xv.z + xv.w;
  #pragma unroll
  for (int off = 1; off < 64; off <<= 1) sum += __shfl_xor(sum, off);
  const float m = sum * (1.f / DD_);
  const float dx = xv.x - m, dy = xv.y - m, dz = xv.z - m, dw = xv.w - m;
  float ss = dx*dx + dy*dy + dz*dz + dw*dw;
  #pragma unroll
  for (int off = 1; off < 64; off <<= 1) ss += __shfl_xor(ss, off);
  const float inv = rsqrtf(ss * (1.f / DD_) + EPS_);
  const float4 sv = *reinterpret_cast<const float4*>(s + lane * 4);
  const float4 bv = *reinterpret_cast<const float4*>(b + lane * 4);
  float4 y;
  y.x = dx * inv * sv.x + bv.x;
  y.y = dy * inv * sv.y + bv.y;
  y.z = dz * inv * sv.z + bv.z;
  y.w = dw * inv * sv.w + bv.w;
  if (outf) *reinterpret_cast<float4*>(outf + (long)row * DD_ + lane * 4) = y;
  if (outb) {
    uint2 pk;
    pk.x = bfbits(y.x) | (bfbits(y.y) << 16);
    pk.y = bfbits(y.z) | (bfbits(y.w) << 16);
    *reinterpret_cast<uint2*>(outb + (long)row * DD_ + lane * 4) = pk;
  }
}

// ---- GEMM: 128x128 tile, BK=64, dbuf gload_lds, counted vmcnt, src-swizzled ----
// EPI 0: bf16 = acc+bias | 1: bf16 = relu | 2: f32 = resid+acc+bias
// EPI 3: qkv: q cols scaled by QSCL; v cols scattered transposed to vt[bh][64][1024]
template<int EPI>
__global__ __launch_bounds__(256)
void k_gemm(const bf16* __restrict__ A, const bf16* __restrict__ Wt,
            const float* __restrict__ bias, const float* __restrict__ resid,
            void* __restrict__ out, bf16* __restrict__ vt, int M, int N, int K) {
  __shared__ alignas(16) char As[2][16384];   // [128 r][128 B], st-swizzled rows
  __shared__ alignas(16) char Bs[2][16384];
  const int t = threadIdx.x, lane = t & 63, wid = t >> 6;
  const int wr = wid >> 1, wc = wid & 1;
  const int g = lane >> 4, c = lane & 15;
  // XCD-aware bijective block swizzle (all grids %8 == 0)
  int flat = blockIdx.y * gridDim.x + blockIdx.x;
  const int cpx = (gridDim.x * gridDim.y) >> 3;
  flat = (flat & 7) * cpx + (flat >> 3);
  const int mbase = (flat / gridDim.x) * 128, nbase = (flat % gridDim.x) * 128;

  const int srow = t >> 3;                       // 0..31 (p adds 32p)
  const int skc = ((t & 7) ^ (srow & 7)) * 8;    // swizzle folded into source
  const bf16* ag = A  + (long)(mbase + srow) * K + skc;
  const bf16* bg = Wt + (long)(nbase + srow) * K + skc;
  const int swz = (c & 7) << 4;

  f32x4 acc[4][4] = {};

  auto gstage = [&](int bi, int k0) {
    #pragma unroll
    for (int p = 0; p < 4; p++) {
      gload_lds16(ag + (long)p * 32 * K + k0, As[bi] + p * 4096 + wid * 1024);
      gload_lds16(bg + (long)p * 32 * K + k0, Bs[bi] + p * 4096 + wid * 1024);
    }
  };

  const int nk = K >> 6;
  gstage(0, 0);
  int cur = 0;
  for (int kt = 0; kt < nk; ++kt) {
    if (kt + 1 < nk) {
      gstage(cur ^ 1, (kt + 1) * 64);
      asm volatile("s_waitcnt vmcnt(8)" ::: "memory");   // prev stage done, next in flight
    } else {
      asm volatile("s_waitcnt vmcnt(0)" ::: "memory");
    }
    __builtin_amdgcn_s_barrier();

    bf16x8 af[4][2], bfr[4][2];
    #pragma unroll
    for (int mi = 0; mi < 4; mi++)
      #pragma unroll
      for (int ks = 0; ks < 2; ks++)
        af[mi][ks] = ld_bf8(As[cur] + (wr * 64 + mi * 16 + c) * 128 + ((ks * 64 + g * 16) ^ swz));
    #pragma unroll
    for (int ni = 0; ni < 4; ni++)
      #pragma unroll
      for (int ks = 0; ks < 2; ks++)
        bfr[ni][ks] = ld_bf8(Bs[cur] + (wc * 64 + ni * 16 + c) * 128 + ((ks * 64 + g * 16) ^ swz));
    __builtin_amdgcn_s_setprio(1);
    #pragma unroll
    for (int mi = 0; mi < 4; mi++)
      #pragma unroll
      for (int ni = 0; ni < 4; ni++)
        #pragma unroll
        for (int ks = 0; ks < 2; ks++)
          acc[mi][ni] = MFMA(af[mi][ks], bfr[ni][ks], acc[mi][ni]);
    __builtin_amdgcn_s_setprio(0);
    __builtin_amdgcn_s_barrier();
    cur ^= 1;
  }

  #pragma unroll
  for (int mi = 0; mi < 4; mi++) {
    #pragma unroll
    for (int ni = 0; ni < 4; ni++) {
      const int colg = nbase + wc * 64 + ni * 16 + c;
      const float bv = bias ? bias[colg] : 0.f;
      if constexpr (EPI == 3) {
        if (nbase < 512) {
          const float qs = (nbase < 256) ? QSCL : 1.0f;
          #pragma unroll
          for (int j = 0; j < 4; j++) {
            const int rowg = mbase + wr * 64 + mi * 16 + g * 4 + j;
            ((bf16*)out)[(long)rowg * N + colg] = (bf16)((acc[mi][ni][j] + bv) * qs);
          }
        } else {
          const int dfull = colg - 512, hh = dfull >> 6, d = dfull & 63;
          const int rowg0 = mbase + wr * 64 + mi * 16 + g * 4;
          uint2 st;
          st.x = bfbits(acc[mi][ni][0] + bv) | (bfbits(acc[mi][ni][1] + bv) << 16);
          st.y = bfbits(acc[mi][ni][2] + bv) | (bfbits(acc[mi][ni][3] + bv) << 16);
          *reinterpret_cast<uint2*>(vt + (long)(((rowg0 >> 10) << 2) + hh) * 65536
                                       + d * 1024 + (rowg0 & 1023)) = st;
        }
      } else {
        #pragma unroll
        for (int j = 0; j < 4; j++) {
          const int rowg = mbase + wr * 64 + mi * 16 + g * 4 + j;
          float v = acc[mi][ni][j] + bv;
          if constexpr (EPI == 0) {
            ((bf16*)out)[(long)rowg * N + colg] = (bf16)v;
          } else if constexpr (EPI == 1) {
            ((bf16*)out)[(long)rowg * N + colg] = (bf16)fmaxf(v, 0.f);
          } else {
            float r = resid ? resid[(long)rowg * N + colg] : 0.f;
            ((float*)out)[(long)rowg * N + colg] = r + v;
          }
        }
      }
    }
  }
}

// ---- flash attention: dbuf K/V staging + counted vmcnt (unchanged, passing) ----
__global__ __launch_bounds__(256)
void k_attn(const bf16* __restrict__ qkv, const bf16* __restrict__ vtg,
            bf16* __restrict__ o) {
  __shared__ alignas(16) char Ks[2][8192];
  __shared__ alignas(16) char Vs[2][8192];
  __shared__ alignas(16) char Ps[8192];
  const int t = threadIdx.x, lane = t & 63, w = t >> 6;
  const int g = lane >> 4, c = lane & 15;
  int flat = blockIdx.y * 16 + blockIdx.x;
  flat = (flat & 7) * 128 + (flat >> 3);
  const int bh = flat >> 4, qt = flat & 15;
  const int b = bh >> 2, h = bh & 3;
  const long tokbase = (long)b * TT;
  const int q_glob = qt * 64 + w * 16 + c;

  bf16x8 qf0 = ld_bf8(qkv + (tokbase + q_glob) * 768 + h * 64 + g * 8);
  bf16x8 qf1 = ld_bf8(qkv + (tokbase + q_glob) * 768 + h * 64 + 32 + g * 8);

  const int sr = t >> 3;
  const int slot = (t & 7) ^ (sr & 7);
  const int swz_c = (c & 7) << 4;
  const bf16* kbase = qkv + 256 + h * 64 + slot * 8;
  const bf16* vbase = vtg + (long)bh * 65536 + slot * 8;
  char* pw = Ps + w * 2048 + c * 128;

#define KSTAGE(bi, jt) do { \
    gload_lds16(kbase + (tokbase + (jt) * 64 + sr) * 768,      Ks[bi] + w * 1024); \
    gload_lds16(kbase + (tokbase + (jt) * 64 + sr + 32) * 768, Ks[bi] + 4096 + w * 1024); \
    gload_lds16(vbase + (long)sr * 1024 + (jt) * 64,           Vs[bi] + w * 1024); \
    gload_lds16(vbase + (long)(sr + 32) * 1024 + (jt) * 64,    Vs[bi] + 4096 + w * 1024); \
  } while (0)

  f32x4 oacc[4] = {};
  float mrun = -1e30f, lrun = 0.f;

  KSTAGE(0, 0);
  int cur = 0;
  for (int jt = 0; jt < 16; ++jt) {
    if (jt + 1 < 16) {
      KSTAGE(cur ^ 1, jt + 1);
      asm volatile("s_waitcnt vmcnt(4)" ::: "memory");
    } else {
      asm volatile("s_waitcnt vmcnt(0)" ::: "memory");
    }
    __builtin_amdgcn_s_barrier();

    f32x4 sacc[4] = {};
    __builtin_amdgcn_s_setprio(1);
    #pragma unroll
    for (int ni = 0; ni < 4; ni++) {
      const char* krow = Ks[cur] + (ni * 16 + c) * 128;
      bf16x8 kf0 = ld_bf8(krow + ((g * 16) ^ swz_c));
      bf16x8 kf1 = ld_bf8(krow + ((64 + g * 16) ^ swz_c));
      sacc[ni] = MFMA(kf0, qf0, sacc[ni]);
      sacc[ni] = MFMA(kf1, qf1, sacc[ni]);
    }
    __builtin_amdgcn_s_setprio(0);

    float m0 = -1e30f;
    #pragma unroll
    for (int ni = 0; ni < 4; ni++)
      #pragma unroll
      for (int j = 0; j < 4; j++) m0 = fmaxf(m0, sacc[ni][j]);
    m0 = fmaxf(m0, __shfl_xor(m0, 16));
    m0 = fmaxf(m0, __shfl_xor(m0, 32));

    if (!__all(m0 <= mrun + 11.5f)) {   // defer-max (T13)
      const float mn = fmaxf(mrun, m0);
      const float al = __builtin_amdgcn_exp2f(mrun - mn);
      mrun = mn;
      lrun *= al;
      #pragma unroll
      for (int nd = 0; nd < 4; nd++)
        #pragma unroll
        for (int j = 0; j < 4; j++) oacc[nd][j] *= al;
    }

    float rs = 0.f;
    unsigned pk[8];
    #pragma unroll
    for (int ni = 0; ni < 4; ni++) {
      float p0 = __builtin_amdgcn_exp2f(sacc[ni][0] - mrun);
      float p1 = __builtin_amdgcn_exp2f(sacc[ni][1] - mrun);
      float p2 = __builtin_amdgcn_exp2f(sacc[ni][2] - mrun);
      float p3 = __builtin_amdgcn_exp2f(sacc[ni][3] - mrun);
      rs += (p0 + p1) + (p2 + p3);
      pk[ni * 2]     = bfbits(p0) | (bfbits(p1) << 16);
      pk[ni * 2 + 1] = bfbits(p2) | (bfbits(p3) << 16);
    }
    rs += __shfl_xor(rs, 16);
    rs += __shfl_xor(rs, 32);
    lrun += rs;

    #pragma unroll
    for (int ni = 0; ni < 4; ni++) {
      uint2 q2; q2.x = pk[ni * 2]; q2.y = pk[ni * 2 + 1];
      *reinterpret_cast<uint2*>(pw + ((ni * 32 + g * 8) ^ swz_c)) = q2;
    }

    __builtin_amdgcn_s_setprio(1);
    #pragma unroll
    for (int kk = 0; kk < 2; kk++) {
      bf16x8 pf = ld_bf8(pw + ((kk * 64 + g * 16) ^ swz_c));
      #pragma unroll
      for (int nd = 0; nd < 4; nd++) {
        bf16x8 vf = ld_bf8(Vs[cur] + (nd * 16 + c) * 128 + ((kk * 64 + g * 16) ^ swz_c));
        oacc[nd] = MFMA(vf, pf, oacc[nd]);
      }
    }
    __builtin_amdgcn_s_setprio(0);
    __builtin_amdgcn_s_barrier();
    cur ^= 1;
  }
#undef KSTAGE

  const float inv = 1.f / lrun;
  bf16* orow = o + (tokbase + q_glob) * 256 + h * 64 + g * 4;
  #pragma unroll
  for (int nd = 0; nd < 4; nd++) {
    uint2 st;
    st.x = bfbits(oacc[nd][0] * inv) | (bfbits(oacc[nd][1] * inv) << 16);
    st.y = bfbits(oacc[nd][2] * inv) | (bfbits(oacc[nd][3] * inv) << 16);
    *reinterpret_cast<uint2*>(orow + nd * 16) = st;
  }
}

// ---- host ----
extern "C" void kernel_launch(void* const* d_in, const int* in_sizes, int n_in,
                              void* d_out, int out_size, void* d_ws, size_t ws_size,
                              hipStream_t stream) {
  const float* x     = (const float*)d_in[0];
  const float* Win   = (const float*)d_in[2];
  const float* b_in  = (const float*)d_in[3];
  const float* ln1_s = (const float*)d_in[4];
  const float* ln1_b = (const float*)d_in[5];
  const float* Wq    = (const float*)d_in[6];
  const float* bq    = (const float*)d_in[7];
  const float* Wk    = (const float*)d_in[8];
  const float* bk    = (const float*)d_in[9];
  const float* Wv    = (const float*)d_in[10];
  const float* bv    = (const float*)d_in[11];
  const float* Wo    = (const float*)d_in[12];
  const float* bo    = (const float*)d_in[13];
  const float* ln2_s = (const float*)d_in[14];
  const float* ln2_b = (const float*)d_in[15];
  const float* W1    = (const float*)d_in[16];
  const float* b1    = (const float*)d_in[17];
  const float* W2    = (const float*)d_in[18];
  const float* b2    = (const float*)d_in[19];
  const float* lno_s = (const float*)d_in[20];
  const float* lno_b = (const float*)d_in[21];
  float* out = (float*)d_out;

  char* ws = (char*)d_ws;
  size_t off = 0;
  auto alloc = [&](size_t bytes) -> void* {
    void* p = ws + off; off += (bytes + 255) & ~(size_t)255; return p;
  };
  float* e    = (float*)alloc((size_t)MTOK * DD_ * 4);
  bf16* e_bf  = (bf16*)alloc((size_t)MTOK * DD_ * 2);
  bf16* qkvb  = (bf16*)alloc((size_t)MTOK * 768 * 2);
  bf16* vtb   = (bf16*)alloc((size_t)MTOK * DD_ * 2);
  bf16* ob    = (bf16*)alloc((size_t)MTOK * DD_ * 2);
  bf16* hb    = (bf16*)alloc((size_t)MTOK * FF_ * 2);
  bf16* x_bf  = (bf16*)hb;   // alias: x_bf consumed before hb first written
  bf16* Wint  = (bf16*)alloc((size_t)DD_ * KPAD * 2);
  bf16* Wqkvt = (bf16*)alloc((size_t)LL * 768 * DD_ * 2);
  bf16* Wot   = (bf16*)alloc((size_t)LL * DD_ * DD_ * 2);
  bf16* W1t   = (bf16*)alloc((size_t)LL * DD_ * FF_ * 2);
  bf16* W2t   = (bf16*)alloc((size_t)LL * FF_ * DD_ * 2);
  float* bqkv = (float*)alloc((size_t)LL * 768 * 4);

  dim3 blk(256);

  k_convert_pad<<<(MTOK * (KPAD / 4) + 255) / 256, 256, 0, stream>>>(x, x_bf);
  k_wt_convert<<<(DD_ * KPAD + 255) / 256, 256, 0, stream>>>(Win, Wint, IDIM_, DD_, KPAD);
  k_wt_all<<<dim3(64, 24), blk, 0, stream>>>(Wq, Wk, Wv, Wo, W1, W2, Wqkvt, Wot, W1t, W2t);
  k_bias_concat<<<(LL * 768 + 255) / 256, 256, 0, stream>>>(bq, bk, bv, bqkv);

  k_gemm<2><<<dim3(2, 128), blk, 0, stream>>>(x_bf, Wint, b_in, nullptr, e, nullptr, MTOK, DD_, KPAD);

  const long DDW = (long)DD_ * DD_;
  const long DFF = (long)DD_ * FF_;
  for (int i = 0; i < LL; i++) {
    k_ln<<<MTOK / 4, 256, 0, stream>>>(e, e, e_bf, ln1_s + i * DD_, ln1_b + i * DD_);
    k_gemm<3><<<dim3(6, 128), blk, 0, stream>>>(e_bf, Wqkvt + (long)i * 768 * DD_, bqkv + i * 768,
                                                nullptr, qkvb, vtb, MTOK, 768, DD_);
    k_attn<<<dim3(16, 64), blk, 0, stream>>>(qkvb, vtb, ob);
    k_gemm<2><<<dim3(2, 128), blk, 0, stream>>>(ob, Wot + i * DDW, bo + i * DD_, e, e, nullptr, MTOK, DD_, DD_);
    k_ln<<<MTOK / 4, 256, 0, stream>>>(e, e, e_bf, ln2_s + i * DD_, ln2_b + i * DD_);
    k_gemm<1><<<dim3(8, 128), blk, 0, stream>>>(e_bf, W1t + i * DFF, b1 + i * FF_, nullptr, hb, nullptr, MTOK, FF_, DD_);
    k_gemm<2><<<dim3(2, 128), blk, 0, stream>>>(hb, W2t + i * DFF, b2 + i * DD_, e, e, nullptr, MTOK, DD_, FF_);
  }
  k_ln<<<MTOK / 4, 256, 0, stream>>>(e, out, nullptr, lno_s, lno_b);
}

// Round 6
// 575.937 us; speedup vs baseline: 1.1997x; 1.1997x over previous
//
#include <hip/hip_runtime.h>
#include <hip/hip_bf16.h>

// ---- problem constants ----
#define BB    16
#define TT    1024
#define MTOK  (BB*TT)     // 16384 tokens
#define IDIM_ 345
#define KPAD  384         // padded to /64 for BK=64
#define LL    4
#define DD_   256
#define FF_   1024
#define EPS_  1e-5f
#define QSCL  0.18033688f   // 0.125 * log2(e)

typedef __bf16 bf16;
typedef bf16 bf16x8 __attribute__((ext_vector_type(8)));
typedef float f32x4 __attribute__((ext_vector_type(4)));

static __device__ __forceinline__ f32x4 MFMA(bf16x8 a, bf16x8 b, f32x4 c) {
  return __builtin_amdgcn_mfma_f32_16x16x32_bf16(a, b, c, 0, 0, 0);
}
static __device__ __forceinline__ unsigned bfbits(float x) {
  return (unsigned)__builtin_bit_cast(unsigned short, (bf16)x);
}
static __device__ __forceinline__ bf16x8 ld_bf8(const void* p) {
  return *reinterpret_cast<const bf16x8*>(p);
}
static __device__ __forceinline__ void gload_lds16(const bf16* g, void* l) {
  __builtin_amdgcn_global_load_lds(
      (const __attribute__((address_space(1))) void*)g,
      (__attribute__((address_space(3))) void*)l, 16, 0, 0);
}

// ---- conversion kernels ----
__global__ void k_convert_pad(const float* __restrict__ src, bf16* __restrict__ dst) {
  int idx = blockIdx.x * 256 + threadIdx.x;          // quad index
  if (idx >= MTOK * (KPAD / 4)) return;
  int r = idx / (KPAD / 4), c0 = (idx % (KPAD / 4)) * 4;
  const float* s = src + (long)r * IDIM_ + c0;
  float v0 = (c0 + 0 < IDIM_) ? s[0] : 0.f;
  float v1 = (c0 + 1 < IDIM_) ? s[1] : 0.f;
  float v2 = (c0 + 2 < IDIM_) ? s[2] : 0.f;
  float v3 = (c0 + 3 < IDIM_) ? s[3] : 0.f;
  uint2 pk;
  pk.x = bfbits(v0) | (bfbits(v1) << 16);
  pk.y = bfbits(v2) | (bfbits(v3) << 16);
  *reinterpret_cast<uint2*>(dst + (long)r * KPAD + c0) = pk;
}

__global__ void k_wt_convert(const float* __restrict__ src, bf16* __restrict__ dst,
                             int K, int N, int Kp) {
  int idx = blockIdx.x * 256 + threadIdx.x;
  if (idx >= N * Kp) return;
  int n = idx / Kp, kk = idx % Kp;
  dst[idx] = (kk < K) ? (bf16)src[(long)kk * N + n] : (bf16)0.f;
}

// LDS-tiled 64x64 transpose: [K,N] f32 -> [N,K] bf16
__global__ __launch_bounds__(256)
void k_wt_all(const float* __restrict__ Wq, const float* __restrict__ Wk,
              const float* __restrict__ Wv, const float* __restrict__ Wo,
              const float* __restrict__ W1, const float* __restrict__ W2,
              bf16* __restrict__ Wqkvt, bf16* __restrict__ Wot,
              bf16* __restrict__ W1t, bf16* __restrict__ W2t) {
  __shared__ float tile[64][65];
  const int s = blockIdx.y, m = s >> 2, i = s & 3;
  const float* src; bf16* dst; int K, N;
  switch (m) {
    case 0: src = Wq + (long)i*65536;  dst = Wqkvt + (long)i*196608;          K=256;  N=256;  break;
    case 1: src = Wk + (long)i*65536;  dst = Wqkvt + (long)i*196608 + 65536;  K=256;  N=256;  break;
    case 2: src = Wv + (long)i*65536;  dst = Wqkvt + (long)i*196608 + 131072; K=256;  N=256;  break;
    case 3: src = Wo + (long)i*65536;  dst = Wot + (long)i*65536;             K=256;  N=256;  break;
    case 4: src = W1 + (long)i*262144; dst = W1t + (long)i*262144;            K=256;  N=1024; break;
    default:src = W2 + (long)i*262144; dst = W2t + (long)i*262144;            K=1024; N=256;  break;
  }
  const int tiles_n = N >> 6, ntiles = (K >> 6) * tiles_n;
  if (blockIdx.x >= ntiles) return;
  const int tk = blockIdx.x / tiles_n, tn = blockIdx.x % tiles_n;
  const int t = threadIdx.x, rq = t >> 6, cl = t & 63;
  #pragma unroll
  for (int i2 = 0; i2 < 16; i2++)
    tile[rq * 16 + i2][cl] = src[(long)(tk * 64 + rq * 16 + i2) * N + tn * 64 + cl];
  __syncthreads();
  #pragma unroll
  for (int i2 = 0; i2 < 16; i2++)
    dst[(long)(tn * 64 + rq * 16 + i2) * K + tk * 64 + cl] = (bf16)tile[cl][rq * 16 + i2];
}

__global__ void k_bias_concat(const float* __restrict__ bq, const float* __restrict__ bk,
                              const float* __restrict__ bv, float* __restrict__ bqkv) {
  int idx = blockIdx.x * 256 + threadIdx.x;
  if (idx >= LL * 768) return;
  int i = idx / 768, j = idx % 768;
  float v = (j < 256) ? bq[i*256 + j] : (j < 512 ? bk[i*256 + j - 256] : bv[i*256 + j - 512]);
  bqkv[idx] = v;
}

// ---- LayerNorm: one wave per row of 256 ----
__global__ __launch_bounds__(256)
void k_ln(const float* __restrict__ in, float* __restrict__ outf,
          bf16* __restrict__ outb, const float* __restrict__ s,
          const float* __restrict__ b) {
  const int wave = threadIdx.x >> 6, lane = threadIdx.x & 63;
  const int row = blockIdx.x * 4 + wave;
  const float4 xv = *reinterpret_cast<const float4*>(in + (long)row * DD_ + lane * 4);
  float sum = xv.x + xv.y + xv.z + xv.w;
  #pragma unroll
  for (int off = 1; off < 64; off <<= 1) sum += __shfl_xor(sum, off);
  const float m = sum * (1.f / DD_);
  const float dx = xv.x - m, dy = xv.y - m, dz = xv.z - m, dw = xv.w - m;
  float ss = dx*dx + dy*dy + dz*dz + dw*dw;
  #pragma unroll
  for (int off = 1; off < 64; off <<= 1) ss += __shfl_xor(ss, off);
  const float inv = rsqrtf(ss * (1.f / DD_) + EPS_);
  const float4 sv = *reinterpret_cast<const float4*>(s + lane * 4);
  const float4 bv = *reinterpret_cast<const float4*>(b + lane * 4);
  float4 y;
  y.x = dx * inv * sv.x + bv.x;
  y.y = dy * inv * sv.y + bv.y;
  y.z = dz * inv * sv.z + bv.z;
  y.w = dw * inv * sv.w + bv.w;
  if (outf) *reinterpret_cast<float4*>(outf + (long)row * DD_ + lane * 4) = y;
  if (outb) {
    uint2 pk;
    pk.x = bfbits(y.x) | (bfbits(y.y) << 16);
    pk.y = bfbits(y.z) | (bfbits(y.w) << 16);
    *reinterpret_cast<uint2*>(outb + (long)row * DD_ + lane * 4) = pk;
  }
}

// ---- GEMM: 64x64 tile, BK=64, double-buffered gload_lds, counted vmcnt ----
// (round-4 proven config)
template<int EPI>
__global__ __launch_bounds__(256)
void k_gemm(const bf16* __restrict__ A, const bf16* __restrict__ Wt,
            const float* __restrict__ bias, const float* __restrict__ resid,
            void* __restrict__ out, bf16* __restrict__ vt, int M, int N, int K) {
  __shared__ alignas(16) char As[2][8192];   // [64 r][64 k] bf16, src-preswizzled
  __shared__ alignas(16) char Bs[2][8192];
  const int t = threadIdx.x, lane = t & 63, wid = t >> 6;
  const int wr = wid >> 1, wc = wid & 1;
  const int g = lane >> 4, c = lane & 15;
  int flat = blockIdx.y * gridDim.x + blockIdx.x;
  const int cpx = (gridDim.x * gridDim.y) >> 3;
  flat = (flat & 7) * cpx + (flat >> 3);
  const int mbase = (flat / gridDim.x) * 64, nbase = (flat % gridDim.x) * 64;

  const int srow = t >> 3;
  const int skc = (((t & 7) ^ (srow & 7)) * 8);
  const bf16* ag = A  + (long)(mbase + srow) * K + skc;
  const bf16* bg = Wt + (long)(nbase + srow) * K + skc;
  const int swz = (c & 7) << 4;

  f32x4 acc[2][2] = {};

#define GSTAGE(bi, k0) do { \
    gload_lds16(ag + (k0),                  As[bi] + wid * 1024); \
    gload_lds16(ag + (k0) + 32 * (long)K,   As[bi] + 4096 + wid * 1024); \
    gload_lds16(bg + (k0),                  Bs[bi] + wid * 1024); \
    gload_lds16(bg + (k0) + 32 * (long)K,   Bs[bi] + 4096 + wid * 1024); \
  } while (0)

  const int nk = K >> 6;
  GSTAGE(0, 0);
  int cur = 0;
  for (int kt = 0; kt < nk; ++kt) {
    if (kt + 1 < nk) {
      GSTAGE(cur ^ 1, (kt + 1) * 64);
      asm volatile("s_waitcnt vmcnt(4)" ::: "memory");
    } else {
      asm volatile("s_waitcnt vmcnt(0)" ::: "memory");
    }
    __builtin_amdgcn_s_barrier();

    bf16x8 af[2][2], bfr[2][2];
    #pragma unroll
    for (int mi = 0; mi < 2; mi++)
      #pragma unroll
      for (int ks = 0; ks < 2; ks++)
        af[mi][ks] = ld_bf8(As[cur] + (wr * 32 + mi * 16 + c) * 128 + ((ks * 64 + g * 16) ^ swz));
    #pragma unroll
    for (int ni = 0; ni < 2; ni++)
      #pragma unroll
      for (int ks = 0; ks < 2; ks++)
        bfr[ni][ks] = ld_bf8(Bs[cur] + (wc * 32 + ni * 16 + c) * 128 + ((ks * 64 + g * 16) ^ swz));
    __builtin_amdgcn_s_setprio(1);
    #pragma unroll
    for (int mi = 0; mi < 2; mi++)
      #pragma unroll
      for (int ni = 0; ni < 2; ni++)
        #pragma unroll
        for (int ks = 0; ks < 2; ks++)
          acc[mi][ni] = MFMA(af[mi][ks], bfr[ni][ks], acc[mi][ni]);
    __builtin_amdgcn_s_setprio(0);
    __builtin_amdgcn_s_barrier();
    cur ^= 1;
  }
#undef GSTAGE

  #pragma unroll
  for (int mi = 0; mi < 2; mi++) {
    #pragma unroll
    for (int ni = 0; ni < 2; ni++) {
      const int colg = nbase + wc * 32 + ni * 16 + c;
      const float bv = bias ? bias[colg] : 0.f;
      if constexpr (EPI == 3) {
        if (nbase < 512) {
          const float qs = (nbase < 256) ? QSCL : 1.0f;
          #pragma unroll
          for (int j = 0; j < 4; j++) {
            const int rowg = mbase + wr * 32 + mi * 16 + g * 4 + j;
            ((bf16*)out)[(long)rowg * N + colg] = (bf16)((acc[mi][ni][j] + bv) * qs);
          }
        } else {
          const int dfull = colg - 512, hh = dfull >> 6, d = dfull & 63;
          const int rowg0 = mbase + wr * 32 + mi * 16 + g * 4;
          uint2 st;
          st.x = bfbits(acc[mi][ni][0] + bv) | (bfbits(acc[mi][ni][1] + bv) << 16);
          st.y = bfbits(acc[mi][ni][2] + bv) | (bfbits(acc[mi][ni][3] + bv) << 16);
          *reinterpret_cast<uint2*>(vt + (long)(((rowg0 >> 10) << 2) + hh) * 65536
                                       + d * 1024 + (rowg0 & 1023)) = st;
        }
      } else {
        #pragma unroll
        for (int j = 0; j < 4; j++) {
          const int rowg = mbase + wr * 32 + mi * 16 + g * 4 + j;
          float v = acc[mi][ni][j] + bv;
          if constexpr (EPI == 0) {
            ((bf16*)out)[(long)rowg * N + colg] = (bf16)v;
          } else if constexpr (EPI == 1) {
            ((bf16*)out)[(long)rowg * N + colg] = (bf16)fmaxf(v, 0.f);
          } else {
            float r = resid ? resid[(long)rowg * N + colg] : 0.f;
            ((float*)out)[(long)rowg * N + colg] = r + v;
          }
        }
      }
    }
  }
}

// ---- flash attention: dbuf K/V + counted vmcnt + softmax/PV interleave ----
__global__ __launch_bounds__(256)
void k_attn(const bf16* __restrict__ qkv, const bf16* __restrict__ vtg,
            bf16* __restrict__ o) {
  __shared__ alignas(16) char Ks[2][8192];
  __shared__ alignas(16) char Vs[2][8192];
  __shared__ alignas(16) char Ps[8192];
  const int t = threadIdx.x, lane = t & 63, w = t >> 6;
  const int g = lane >> 4, c = lane & 15;
  int flat = blockIdx.y * 16 + blockIdx.x;
  flat = (flat & 7) * 128 + (flat >> 3);
  const int bh = flat >> 4, qt = flat & 15;
  const int b = bh >> 2, h = bh & 3;
  const long tokbase = (long)b * TT;
  const int q_glob = qt * 64 + w * 16 + c;

  bf16x8 qf0 = ld_bf8(qkv + (tokbase + q_glob) * 768 + h * 64 + g * 8);
  bf16x8 qf1 = ld_bf8(qkv + (tokbase + q_glob) * 768 + h * 64 + 32 + g * 8);

  const int sr = t >> 3;
  const int slot = (t & 7) ^ (sr & 7);
  const int swz_c = (c & 7) << 4;
  const bf16* kbase = qkv + 256 + h * 64 + slot * 8;
  const bf16* vbase = vtg + (long)bh * 65536 + slot * 8;
  char* pw = Ps + w * 2048 + c * 128;

#define KSTAGE(bi, jt) do { \
    gload_lds16(kbase + (tokbase + (jt) * 64 + sr) * 768,      Ks[bi] + w * 1024); \
    gload_lds16(kbase + (tokbase + (jt) * 64 + sr + 32) * 768, Ks[bi] + 4096 + w * 1024); \
    gload_lds16(vbase + (long)sr * 1024 + (jt) * 64,           Vs[bi] + w * 1024); \
    gload_lds16(vbase + (long)(sr + 32) * 1024 + (jt) * 64,    Vs[bi] + 4096 + w * 1024); \
  } while (0)

  f32x4 oacc[4] = {};
  float mrun = -1e30f, lrun = 0.f;

  KSTAGE(0, 0);
  int cur = 0;
  for (int jt = 0; jt < 16; ++jt) {
    if (jt + 1 < 16) {
      KSTAGE(cur ^ 1, jt + 1);
      asm volatile("s_waitcnt vmcnt(4)" ::: "memory");
    } else {
      asm volatile("s_waitcnt vmcnt(0)" ::: "memory");
    }
    __builtin_amdgcn_s_barrier();

    // S^T = K · Q^T (pre-scaled): C[kv][q], lane owns q=c
    f32x4 sacc[4] = {};
    __builtin_amdgcn_s_setprio(1);
    #pragma unroll
    for (int ni = 0; ni < 4; ni++) {
      const char* krow = Ks[cur] + (ni * 16 + c) * 128;
      bf16x8 kf0 = ld_bf8(krow + ((g * 16) ^ swz_c));
      bf16x8 kf1 = ld_bf8(krow + ((64 + g * 16) ^ swz_c));
      sacc[ni] = MFMA(kf0, qf0, sacc[ni]);
      sacc[ni] = MFMA(kf1, qf1, sacc[ni]);
    }
    __builtin_amdgcn_s_setprio(0);

    // max: two independent sub-chains, then cross-lane
    float mA = fmaxf(fmaxf(fmaxf(sacc[0][0], sacc[0][1]), fmaxf(sacc[0][2], sacc[0][3])),
                     fmaxf(fmaxf(sacc[1][0], sacc[1][1]), fmaxf(sacc[1][2], sacc[1][3])));
    float mB = fmaxf(fmaxf(fmaxf(sacc[2][0], sacc[2][1]), fmaxf(sacc[2][2], sacc[2][3])),
                     fmaxf(fmaxf(sacc[3][0], sacc[3][1]), fmaxf(sacc[3][2], sacc[3][3])));
    float m0 = fmaxf(mA, mB);
    m0 = fmaxf(m0, __shfl_xor(m0, 16));
    m0 = fmaxf(m0, __shfl_xor(m0, 32));

    if (!__all(m0 <= mrun + 11.5f)) {   // defer-max (T13)
      const float mn = fmaxf(mrun, m0);
      const float al = __builtin_amdgcn_exp2f(mrun - mn);
      mrun = mn;
      lrun *= al;
      #pragma unroll
      for (int nd = 0; nd < 4; nd++)
        #pragma unroll
        for (int j = 0; j < 4; j++) oacc[nd][j] *= al;
    }

    // interleave: exp/pack kv 0..31 -> PV(kk=0) -> exp/pack kv 32..63 -> PV(kk=1)
    float rs0 = 0.f, rs1 = 0.f;
    #pragma unroll
    for (int ni = 0; ni < 2; ni++) {
      float p0 = __builtin_amdgcn_exp2f(sacc[ni][0] - mrun);
      float p1 = __builtin_amdgcn_exp2f(sacc[ni][1] - mrun);
      float p2 = __builtin_amdgcn_exp2f(sacc[ni][2] - mrun);
      float p3 = __builtin_amdgcn_exp2f(sacc[ni][3] - mrun);
      rs0 += (p0 + p1) + (p2 + p3);
      uint2 q2;
      q2.x = bfbits(p0) | (bfbits(p1) << 16);
      q2.y = bfbits(p2) | (bfbits(p3) << 16);
      *reinterpret_cast<uint2*>(pw + ((ni * 32 + g * 8) ^ swz_c)) = q2;
    }
    {
      bf16x8 pf = ld_bf8(pw + ((g * 16) ^ swz_c));
      __builtin_amdgcn_s_setprio(1);
      #pragma unroll
      for (int nd = 0; nd < 4; nd++) {
        bf16x8 vf = ld_bf8(Vs[cur] + (nd * 16 + c) * 128 + ((g * 16) ^ swz_c));
        oacc[nd] = MFMA(vf, pf, oacc[nd]);
      }
      __builtin_amdgcn_s_setprio(0);
    }
    #pragma unroll
    for (int ni = 2; ni < 4; ni++) {
      float p0 = __builtin_amdgcn_exp2f(sacc[ni][0] - mrun);
      float p1 = __builtin_amdgcn_exp2f(sacc[ni][1] - mrun);
      float p2 = __builtin_amdgcn_exp2f(sacc[ni][2] - mrun);
      float p3 = __builtin_amdgcn_exp2f(sacc[ni][3] - mrun);
      rs1 += (p0 + p1) + (p2 + p3);
      uint2 q2;
      q2.x = bfbits(p0) | (bfbits(p1) << 16);
      q2.y = bfbits(p2) | (bfbits(p3) << 16);
      *reinterpret_cast<uint2*>(pw + ((ni * 32 + g * 8) ^ swz_c)) = q2;
    }
    {
      bf16x8 pf = ld_bf8(pw + ((64 + g * 16) ^ swz_c));
      __builtin_amdgcn_s_setprio(1);
      #pragma unroll
      for (int nd = 0; nd < 4; nd++) {
        bf16x8 vf = ld_bf8(Vs[cur] + (nd * 16 + c) * 128 + ((64 + g * 16) ^ swz_c));
        oacc[nd] = MFMA(vf, pf, oacc[nd]);
      }
      __builtin_amdgcn_s_setprio(0);
    }
    float rs = rs0 + rs1;
    rs += __shfl_xor(rs, 16);
    rs += __shfl_xor(rs, 32);
    lrun += rs;

    __builtin_amdgcn_s_barrier();
    cur ^= 1;
  }
#undef KSTAGE

  const float inv = 1.f / lrun;
  bf16* orow = o + (tokbase + q_glob) * 256 + h * 64 + g * 4;
  #pragma unroll
  for (int nd = 0; nd < 4; nd++) {
    uint2 st;
    st.x = bfbits(oacc[nd][0] * inv) | (bfbits(oacc[nd][1] * inv) << 16);
    st.y = bfbits(oacc[nd][2] * inv) | (bfbits(oacc[nd][3] * inv) << 16);
    *reinterpret_cast<uint2*>(orow + nd * 16) = st;
  }
}

// ---- host ----
extern "C" void kernel_launch(void* const* d_in, const int* in_sizes, int n_in,
                              void* d_out, int out_size, void* d_ws, size_t ws_size,
                              hipStream_t stream) {
  const float* x     = (const float*)d_in[0];
  const float* Win   = (const float*)d_in[2];
  const float* b_in  = (const float*)d_in[3];
  const float* ln1_s = (const float*)d_in[4];
  const float* ln1_b = (const float*)d_in[5];
  const float* Wq    = (const float*)d_in[6];
  const float* bq    = (const float*)d_in[7];
  const float* Wk    = (const float*)d_in[8];
  const float* bk    = (const float*)d_in[9];
  const float* Wv    = (const float*)d_in[10];
  const float* bv    = (const float*)d_in[11];
  const float* Wo    = (const float*)d_in[12];
  const float* bo    = (const float*)d_in[13];
  const float* ln2_s = (const float*)d_in[14];
  const float* ln2_b = (const float*)d_in[15];
  const float* W1    = (const float*)d_in[16];
  const float* b1    = (const float*)d_in[17];
  const float* W2    = (const float*)d_in[18];
  const float* b2    = (const float*)d_in[19];
  const float* lno_s = (const float*)d_in[20];
  const float* lno_b = (const float*)d_in[21];
  float* out = (float*)d_out;

  char* ws = (char*)d_ws;
  size_t off = 0;
  auto alloc = [&](size_t bytes) -> void* {
    void* p = ws + off; off += (bytes + 255) & ~(size_t)255; return p;
  };
  float* e    = (float*)alloc((size_t)MTOK * DD_ * 4);
  bf16* e_bf  = (bf16*)alloc((size_t)MTOK * DD_ * 2);
  bf16* qkvb  = (bf16*)alloc((size_t)MTOK * 768 * 2);
  bf16* vtb   = (bf16*)alloc((size_t)MTOK * DD_ * 2);
  bf16* ob    = (bf16*)alloc((size_t)MTOK * DD_ * 2);
  bf16* hb    = (bf16*)alloc((size_t)MTOK * FF_ * 2);
  bf16* x_bf  = (bf16*)hb;   // alias: x_bf consumed before hb first written
  bf16* Wint  = (bf16*)alloc((size_t)DD_ * KPAD * 2);
  bf16* Wqkvt = (bf16*)alloc((size_t)LL * 768 * DD_ * 2);
  bf16* Wot   = (bf16*)alloc((size_t)LL * DD_ * DD_ * 2);
  bf16* W1t   = (bf16*)alloc((size_t)LL * DD_ * FF_ * 2);
  bf16* W2t   = (bf16*)alloc((size_t)LL * FF_ * DD_ * 2);
  float* bqkv = (float*)alloc((size_t)LL * 768 * 4);

  dim3 blk(256);

  k_convert_pad<<<(MTOK * (KPAD / 4) + 255) / 256, 256, 0, stream>>>(x, x_bf);
  k_wt_convert<<<(DD_ * KPAD + 255) / 256, 256, 0, stream>>>(Win, Wint, IDIM_, DD_, KPAD);
  k_wt_all<<<dim3(64, 24), blk, 0, stream>>>(Wq, Wk, Wv, Wo, W1, W2, Wqkvt, Wot, W1t, W2t);
  k_bias_concat<<<(LL * 768 + 255) / 256, 256, 0, stream>>>(bq, bk, bv, bqkv);

  k_gemm<2><<<dim3(4, 256), blk, 0, stream>>>(x_bf, Wint, b_in, nullptr, e, nullptr, MTOK, DD_, KPAD);

  const long DDW = (long)DD_ * DD_;
  const long DFF = (long)DD_ * FF_;
  for (int i = 0; i < LL; i++) {
    k_ln<<<MTOK / 4, 256, 0, stream>>>(e, e, e_bf, ln1_s + i * DD_, ln1_b + i * DD_);
    k_gemm<3><<<dim3(12, 256), blk, 0, stream>>>(e_bf, Wqkvt + (long)i * 768 * DD_, bqkv + i * 768,
                                                 nullptr, qkvb, vtb, MTOK, 768, DD_);
    k_attn<<<dim3(16, 64), blk, 0, stream>>>(qkvb, vtb, ob);
    k_gemm<2><<<dim3(4, 256), blk, 0, stream>>>(ob, Wot + i * DDW, bo + i * DD_, e, e, nullptr, MTOK, DD_, DD_);
    k_ln<<<MTOK / 4, 256, 0, stream>>>(e, e, e_bf, ln2_s + i * DD_, ln2_b + i * DD_);
    k_gemm<1><<<dim3(16, 256), blk, 0, stream>>>(e_bf, W1t + i * DFF, b1 + i * FF_, nullptr, hb, nullptr, MTOK, FF_, DD_);
    k_gemm<2><<<dim3(4, 256), blk, 0, stream>>>(hb, W2t + i * DFF, b2 + i * DD_, e, e, nullptr, MTOK, DD_, FF_);
  }
  k_ln<<<MTOK / 4, 256, 0, stream>>>(e, out, nullptr, lno_s, lno_b);
}